// Round 13
// baseline (143.310 us; speedup 1.0000x reference)
//
#include <hip/hip_runtime.h>
#include <math.h>

#define EPSF 1e-8f
#define BIGF 1e30f
#define NSEG 64        // face-window segments per tile (sorted order)
#define NBIN 256       // z-sort bins

__device__ __forceinline__ float fastrcp(float x) {
    float y;
    asm("v_rcp_f32 %0, %1" : "=v"(y) : "v"(x));   // ~1 ulp; perf-filter only
    return y;
}

// ---------------------------------------------------------------------------
// Bit-exact projection of one vertex (numpy f32 op sequence, _rn ops only).
// ---------------------------------------------------------------------------
__device__ __forceinline__ void project_vert(
    const float* __restrict__ Km, const float* __restrict__ Rm,
    const float* __restrict__ tv,
    float vx, float vy, float vz, float& X, float& Y, float& Z)
{
    float a;
    a = __fadd_rn(__fmul_rn(vx, Rm[0]), __fmul_rn(vy, Rm[1]));
    a = __fadd_rn(a, __fmul_rn(vz, Rm[2]));
    float c0 = __fadd_rn(a, tv[0]);
    a = __fadd_rn(__fmul_rn(vx, Rm[3]), __fmul_rn(vy, Rm[4]));
    a = __fadd_rn(a, __fmul_rn(vz, Rm[5]));
    float c1 = __fadd_rn(a, tv[1]);
    a = __fadd_rn(__fmul_rn(vx, Rm[6]), __fmul_rn(vy, Rm[7]));
    a = __fadd_rn(a, __fmul_rn(vz, Rm[8]));
    float c2 = __fadd_rn(a, tv[2]);

    float u0 = __fadd_rn(__fadd_rn(__fmul_rn(c0, Km[0]), __fmul_rn(c1, Km[1])),
                         __fmul_rn(c2, Km[2]));
    float u1 = __fadd_rn(__fadd_rn(__fmul_rn(c0, Km[3]), __fmul_rn(c1, Km[4])),
                         __fmul_rn(c2, Km[5]));
    X = __fdiv_rn(u0, c2);
    Y = __fdiv_rn(u1, c2);
    Z = c2;
}

// ---------------------------------------------------------------------------
// z-bin (must be recomputed identically in k_prep and k_scatter).
// ---------------------------------------------------------------------------
__device__ __forceinline__ int zbin(bool valid, float zmin)
{
    if (!valid) return NBIN - 1;
    int b = (int)((zmin - 1.0f) * 64.0f);
    return b < 0 ? 0 : (b > NBIN - 1 ? NBIN - 1 : b);
}

// ---------------------------------------------------------------------------
// conservative tile range of a face bbox.
// ---------------------------------------------------------------------------
__device__ __forceinline__ bool tile_range(float4 b, int tilesX, int tilesY,
                                           int& tx0, int& tx1, int& ty0, int& ty1)
{
    if (b.x > b.y) return false;   // invalid marker
    float fx0 = fmaxf(0.0f, ceilf((b.x - 7.5f - 1e-3f) * 0.125f));
    float fx1 = fminf((float)(tilesX - 1), floorf((b.y - 0.5f + 1e-3f) * 0.125f));
    float fy0 = fmaxf(0.0f, ceilf((b.z - 7.5f - 1e-3f) * 0.125f));
    float fy1 = fminf((float)(tilesY - 1), floorf((b.w - 0.5f + 1e-3f) * 0.125f));
    if (fx0 > fx1 || fy0 > fy1) return false;
    tx0 = (int)fx0; tx1 = (int)fx1; ty0 = (int)fy0; ty1 = (int)fy1;
    return true;
}

// ---------------------------------------------------------------------------
// Kernel 1: per-face setup from vertices (byte-identical projection) + zwin
// init + seg_minz init + LDS-aggregated z-histogram.
// rec[3f+0]={y12,x21,y20,x02}  rec[3f+1]={x2,y2,denom,z0}
// rec[3f+2]={z1,z2,face_id_bits,zmin}   box[f]=bbox (empty if invalid)
// ---------------------------------------------------------------------------
__global__ __launch_bounds__(64) void k_prep(
    const float* __restrict__ verts,
    const float* __restrict__ Km, const float* __restrict__ Rm,
    const float* __restrict__ tv, const int* __restrict__ faces,
    float4* __restrict__ rec, float4* __restrict__ box,
    unsigned long long* __restrict__ zwin, unsigned* __restrict__ segminz,
    unsigned* __restrict__ hist, int nF, int P)
{
    __shared__ unsigned sh[NBIN];
    for (int i = threadIdx.x; i < NBIN; i += 64) sh[i] = 0;
    __syncthreads();

    int f = blockIdx.x * blockDim.x + threadIdx.x;
    int stride = gridDim.x * blockDim.x;
    unsigned long long initpk =
        ((unsigned long long)__float_as_uint(BIGF) << 32) | 0x7fffffffu;
    for (int i = f; i < P; i += stride) zwin[i] = initpk;
    for (int i = f; i < NSEG; i += stride) segminz[i] = 0x7f7fffffu; // FLT_MAX

    if (f < nF) {
        int ia = faces[3*f+0], ib = faces[3*f+1], ic = faces[3*f+2];
        float x0, y0, z0, x1, y1, z1, x2, y2, z2;
        project_vert(Km, Rm, tv, verts[3*ia], verts[3*ia+1], verts[3*ia+2], x0, y0, z0);
        project_vert(Km, Rm, tv, verts[3*ib], verts[3*ib+1], verts[3*ib+2], x1, y1, z1);
        project_vert(Km, Rm, tv, verts[3*ic], verts[3*ic+1], verts[3*ic+2], x2, y2, z2);

        float y12 = __fsub_rn(y1, y2);
        float x21 = __fsub_rn(x2, x1);
        float y20 = __fsub_rn(y2, y0);
        float x02 = __fsub_rn(x0, x2);
        float y02 = __fsub_rn(y0, y2);
        float dn  = __fadd_rn(__fmul_rn(y12, x02), __fmul_rn(x21, y02));
        float zmin = fminf(fminf(z0, z1), z2);
        bool valid = (fabsf(dn) > EPSF) && (zmin > EPSF);
        float bxmin, bxmax, bymin, bymax;
        if (valid) {
            bxmin = fminf(fminf(x0, x1), x2) - 0.5f;
            bxmax = fmaxf(fmaxf(x0, x1), x2) + 0.5f;
            bymin = fminf(fminf(y0, y1), y2) - 0.5f;
            bymax = fmaxf(fmaxf(y0, y1), y2) + 0.5f;
        } else {
            bxmin = BIGF; bxmax = -BIGF; bymin = BIGF; bymax = -BIGF;
        }
        rec[3*f+0] = make_float4(y12, x21, y20, x02);
        rec[3*f+1] = make_float4(x2, y2, dn, z0);
        rec[3*f+2] = make_float4(z1, z2, __int_as_float(f), zmin);
        box[f]     = make_float4(bxmin, bxmax, bymin, bymax);
        atomicAdd(&sh[zbin(valid, zmin)], 1u);
    }
    __syncthreads();
    for (int i = threadIdx.x; i < NBIN; i += 64) {
        unsigned c = sh[i];
        if (c) atomicAdd(&hist[i], c);   // fire-and-forget
    }
}

// ---------------------------------------------------------------------------
// Kernel 2: exclusive scan of the NBIN histogram (single block).
// ---------------------------------------------------------------------------
__global__ __launch_bounds__(NBIN) void k_scan(const unsigned* __restrict__ hist,
                                               unsigned* __restrict__ off)
{
    __shared__ unsigned s[NBIN];
    int t = threadIdx.x;
    s[t] = hist[t];
    __syncthreads();
    for (int d = 1; d < NBIN; d <<= 1) {
        unsigned a = (t >= d) ? s[t - d] : 0;
        __syncthreads();
        s[t] += a;
        __syncthreads();
    }
    off[t + 1] = s[t];
    if (t == 0) off[0] = 0;
}

// ---------------------------------------------------------------------------
// Kernel 3: counting-sort scatter. Writes z-sorted rec2 and the 8B/face cull
// stream cullrec={packed u8 tile-range (saturated at 255), zmin bits}, and
// seg_minz (atomicMin, valid faces only). Permutation is timing-dependent but
// the winner rule is a commutative min -> output deterministic.
// ---------------------------------------------------------------------------
__global__ __launch_bounds__(64) void k_scatter(
    const float4* __restrict__ rec, const float4* __restrict__ box,
    const unsigned* __restrict__ off, unsigned* __restrict__ cur,
    float4* __restrict__ rec2, uint2* __restrict__ cullrec,
    unsigned* __restrict__ segminz,
    int nF, int tilesX, int tilesY, int segw)
{
    int f = blockIdx.x * blockDim.x + threadIdx.x;
    if (f >= nF) return;
    float4 b  = box[f];
    float4 r2 = rec[3*f+2];
    float zmin = r2.w;
    bool valid = (b.x <= b.y);
    int bin = zbin(valid, zmin);
    unsigned slot = off[bin] + atomicAdd(&cur[bin], 1u);
    rec2[3*slot+0] = rec[3*f+0];
    rec2[3*slot+1] = rec[3*f+1];
    rec2[3*slot+2] = r2;
    unsigned tr = 0x00FF00FFu;           // empty range (tx0=255 > tx1=0)
    if (valid) {
        int tx0, tx1, ty0, ty1;
        if (tile_range(b, tilesX, tilesY, tx0, tx1, ty0, ty1)) {
            tx0 = min(tx0, 255); tx1 = min(tx1, 255);
            ty0 = min(ty0, 255); ty1 = min(ty1, 255);
            tr = (unsigned)tx0 | ((unsigned)tx1 << 8)
               | ((unsigned)ty0 << 16) | ((unsigned)ty1 << 24);
            atomicMin(&segminz[slot / segw], __float_as_uint(zmin));
        }
    }
    cullrec[slot] = make_uint2(tr, __float_as_uint(zmin));
}

// ---------------------------------------------------------------------------
// Kernel 4: FUSED cull + z-test over z-SORTED faces. Grid (tiles/4, NSEG).
// Wave skips its entire segment if seg_minz can't beat any lane's threshold;
// cull folds a zmin <= wave-max-threshold test into the 8B/face range test.
// Exact path byte-identical to reference; winner = commutative (depth,id) min.
// ---------------------------------------------------------------------------
__global__ __launch_bounds__(256) void k_raster(
    const float4* __restrict__ rec2, const uint2* __restrict__ cullrec,
    const unsigned* __restrict__ segminz,
    unsigned long long* __restrict__ zwin,
    int nF, int W, int H, int tilesX, int nTiles)
{
    __shared__ float  sM[4][64];        // zmin (1 KB), also read as float4
    __shared__ float4 sZ[4][64];        // r2   (4 KB)
    __shared__ float4 sE[4][64][2];     // r0,r1 (8 KB)
    int wid  = threadIdx.x >> 6;
    int lane = threadIdx.x & 63;
    int tile = blockIdx.x * 4 + wid;
    if (tile >= nTiles) return;

    int segw = (nF + NSEG - 1) / NSEG;
    int fbeg = blockIdx.y * segw;
    int fend = min(nF, fbeg + segw);
    if (fbeg >= fend) return;

    int tileX = tile % tilesX, tileY = tile / tilesX;
    int tXc = min(tileX, 255), tYc = min(tileY, 255);
    int tx = lane & 7, ty = lane >> 3;
    int pxi = tileX * 8 + tx;
    int pyi = tileY * 8 + ty;
    bool inimg = (pxi < W) && (pyi < H);
    float px = (float)pxi + 0.5f;
    float py = (float)pyi + 0.5f;
    float cx  = (float)(tileX * 8) + 4.0f;   // pixel centers span cx +/- 3.5
    float cy  = (float)(tileY * 8) + 4.0f;

    int pidx = inimg ? (pyi * W + pxi) : 0;
    unsigned long long seed = zwin[pidx];   // stale reads sound (monotone min)
    float bd = __uint_as_float((unsigned)(seed >> 32));
    int   bf = (int)(unsigned)(seed & 0xffffffffu);

    // wave-max acceptance threshold (background lanes -> inf, no skip)
    float thr = __fmul_rn(bd, 1.001f);
    #pragma unroll
    for (int o = 32; o >= 1; o >>= 1) thr = fmaxf(thr, __shfl_xor(thr, o));
    // segment-level skip: nothing in this z-segment can beat any lane
    if (__uint_as_float(segminz[blockIdx.y]) > thr) return;

    const float4* sM4g = (const float4*)sM[wid];

    uint2 nb = cullrec[min(fbeg + lane, nF - 1)];

    for (int base = fbeg; base < fend; base += 64) {
        uint2 cb = nb;
        if (base + 64 < fend) nb = cullrec[min(base + 64 + lane, nF - 1)];
        // refresh wave-max threshold with improved bd (conservative if stale)
        thr = __fmul_rn(bd, 1.001f);
        #pragma unroll
        for (int o = 32; o >= 1; o >>= 1) thr = fmaxf(thr, __shfl_xor(thr, o));

        int f = base + lane;
        unsigned tr = cb.x;
        float zm = __uint_as_float(cb.y);
        bool pass = (f < fend)
                 && tXc >= (int)(tr & 255) && tXc <= (int)((tr >> 8) & 255)
                 && tYc >= (int)((tr >> 16) & 255) && tYc <= (int)(tr >> 24)
                 && (zm <= thr);
        float4 r0, r1, r2;
        if (pass) {
            r0 = rec2[3*f+0];
            r1 = rec2[3*f+1];
            // conservative edge-vs-tile reject (3.6 > 3.5 px; perf-only)
            float s  = (r1.z > 0.0f) ? 1.0f : -1.0f;
            float dx = cx - r1.x, dy = cy - r1.y;
            float n0c = r0.x * dx + r0.y * dy;
            float n1c = r0.z * dx + r0.w * dy;
            float t0 = s * n0c + 3.6f * (fabsf(r0.x) + fabsf(r0.y));
            float t1 = s * n1c + 3.6f * (fabsf(r0.z) + fabsf(r0.w));
            float t2 = s * (r1.z - n0c - n1c)
                     + 3.6f * (fabsf(r0.x + r0.z) + fabsf(r0.y + r0.w));
            pass = (t0 >= 0.0f) && (t1 >= 0.0f) && (t2 >= 0.0f);
        }
        if (pass) r2 = rec2[3*f+2];
        unsigned long long m = __ballot(pass);
        if (pass) {
            int slot = __popcll(m & ((1ull << lane) - 1ull));
            sM[wid][slot]    = zm;
            sZ[wid][slot]    = r2;
            sE[wid][slot][0] = r0;
            sE[wid][slot][1] = r1;
        }
        int scnt = (int)__popcll(m);

        for (int g = 0; g < scnt; g += 4) {
            float4 z4 = sM4g[g >> 2];
            float zg = fminf(fminf(z4.x, z4.y), fminf(z4.z, z4.w));
            if (!__any(zg <= __fmul_rn(bd, 1.001f))) continue;
            int jend = min(scnt, g + 4);
            for (int j = g; j < jend; ++j) {
                if (!__any(sM[wid][j] <= __fmul_rn(bd, 1.001f))) continue;
                float4 r2b = sZ[wid][j];
                float4 r0b = sE[wid][j][0];
                float4 r1b = sE[wid][j][1];

                float dx = __fsub_rn(px, r1b.x);
                float dy = __fsub_rn(py, r1b.y);
                float n0 = __fadd_rn(__fmul_rn(r0b.x, dx), __fmul_rn(r0b.y, dy));
                float n1 = __fadd_rn(__fmul_rn(r0b.z, dx), __fmul_rn(r0b.w, dy));
                float dn = r1b.z;
                bool dpos = dn > 0.0f;
                bool in0 = (n0 == 0.0f) || ((n0 > 0.0f) == dpos);  // n0/dn >= 0
                bool in1 = (n1 == 0.0f) || ((n1 > 0.0f) == dpos);
                bool cand = in0 && in1;
                if (cand) {
                    float rdn = fastrcp(dn);
                    float w0a = n0 * rdn, w1a = n1 * rdn;
                    float w2a = 1.0f - w0a - w1a;
                    float ss  = 1.0f + fabsf(w0a) + fabsf(w1a);
                    cand = (w2a >= -1e-4f * ss);       // err(w2a) <= 3e-7*ss
                    if (cand) {
                        float iza = w0a * fastrcp(r1b.w) + w1a * fastrcp(r2b.x)
                                  + w2a * fastrcp(r2b.y);
                        float da  = fastrcp(iza);
                        cand = (da <= __fmul_rn(bd, 1.001f));  // err ~1.5e-4
                    }
                }
                if (cand) {   // exact path: byte-identical reference op order
                    float w0 = __fdiv_rn(n0, dn);
                    float w1 = __fdiv_rn(n1, dn);
                    float w2 = __fsub_rn(__fsub_rn(1.0f, w0), w1);
                    if (w2 >= 0.0f) {
                        float a  = __fdiv_rn(w0, r1b.w);
                        float b2 = __fdiv_rn(w1, r2b.x);
                        float c  = __fdiv_rn(w2, r2b.y);
                        float iz = __fadd_rn(__fadd_rn(a, b2), c);
                        if (iz > EPSF) {
                            float d = __fdiv_rn(1.0f, iz);
                            int  fc = __float_as_int(r2b.z);
                            if ((d < bd) || ((d == bd) && (fc < bf))) {
                                bd = d; bf = fc;
                            }
                        }
                    }
                }
            }
        }
    }

    unsigned long long pk =
        ((unsigned long long)__float_as_uint(bd) << 32) | (unsigned int)bf;
    if (inimg && pk < seed) atomicMin(&zwin[pidx], pk);
}

// ---------------------------------------------------------------------------
// Kernel 5: shade. One thread per pixel; recompute winner bary (bit-identical
// op sequence, ORIGINAL rec indexed by face id) and trilinear-sample texture.
// ---------------------------------------------------------------------------
__global__ __launch_bounds__(128) void k_shade(
    const float4* __restrict__ rec,
    const unsigned long long* __restrict__ zwin,
    const float* __restrict__ tex, const float* __restrict__ bgc,
    float* __restrict__ out, int W, int H)
{
    int p = blockIdx.x * blockDim.x + threadIdx.x;
    int P = W * H;
    if (p >= P) return;
    int pxi = p % W, pyi = p / W;
    float px = (float)pxi + 0.5f;
    float py = (float)pyi + 0.5f;

    unsigned long long pk = zwin[p];
    float o0, o1, o2, oa;
    if ((unsigned)(pk >> 32) != __float_as_uint(BIGF)) {
        int f = (int)(pk & 0xffffffffu);
        float4 r0 = rec[3*f+0];
        float4 r1 = rec[3*f+1];
        float4 r2 = rec[3*f+2];
        float dx = __fsub_rn(px, r1.x);
        float dy = __fsub_rn(py, r1.y);
        float n0 = __fadd_rn(__fmul_rn(r0.x, dx), __fmul_rn(r0.y, dy));
        float n1 = __fadd_rn(__fmul_rn(r0.z, dx), __fmul_rn(r0.w, dy));
        float w0 = __fdiv_rn(n0, r1.z);
        float w1 = __fdiv_rn(n1, r1.z);
        float w2 = __fsub_rn(__fsub_rn(1.0f, w0), w1);
        float c0 = __fdiv_rn(w0, fmaxf(r1.w, EPSF));
        float c1 = __fdiv_rn(w1, fmaxf(r2.x, EPSF));
        float c2 = __fdiv_rn(w2, fmaxf(r2.y, EPSF));
        float s  = __fadd_rn(__fadd_rn(c0, c1), c2);
        s = fmaxf(s, EPSF);
        c0 = __fdiv_rn(c0, s);
        c1 = __fdiv_rn(c1, s);
        c2 = __fdiv_rn(c2, s);
        float p0 = __fmul_rn(fminf(fmaxf(c0, 0.0f), 1.0f), 7.0f);
        float p1 = __fmul_rn(fminf(fmaxf(c1, 0.0f), 1.0f), 7.0f);
        float p2 = __fmul_rn(fminf(fmaxf(c2, 0.0f), 1.0f), 7.0f);
        int i0 = (int)floorf(p0); i0 = i0 < 0 ? 0 : (i0 > 6 ? 6 : i0);
        int i1 = (int)floorf(p1); i1 = i1 < 0 ? 0 : (i1 > 6 ? 6 : i1);
        int i2 = (int)floorf(p2); i2 = i2 < 0 ? 0 : (i2 > 6 ? 6 : i2);
        float f0 = __fsub_rn(p0, (float)i0);
        float f1 = __fsub_rn(p1, (float)i1);
        float f2 = __fsub_rn(p2, (float)i2);
        const float* tb = tex + (size_t)f * (512 * 3);
        float a0 = 0.0f, a1 = 0.0f, a2 = 0.0f;
        #pragma unroll
        for (int d0 = 0; d0 < 2; ++d0) {
            float wx = d0 ? f0 : __fsub_rn(1.0f, f0);
            #pragma unroll
            for (int d1 = 0; d1 < 2; ++d1) {
                float wy = d1 ? f1 : __fsub_rn(1.0f, f1);
                #pragma unroll
                for (int d2 = 0; d2 < 2; ++d2) {
                    float wz = d2 ? f2 : __fsub_rn(1.0f, f2);
                    float w = __fmul_rn(__fmul_rn(wx, wy), wz);
                    int idx = (((i0 + d0) << 6) + ((i1 + d1) << 3) + (i2 + d2)) * 3;
                    a0 = __fadd_rn(a0, __fmul_rn(w, fmaxf(tb[idx + 0], 0.0f)));
                    a1 = __fadd_rn(a1, __fmul_rn(w, fmaxf(tb[idx + 1], 0.0f)));
                    a2 = __fadd_rn(a2, __fmul_rn(w, fmaxf(tb[idx + 2], 0.0f)));
                }
            }
        }
        o0 = a0; o1 = a1; o2 = a2; oa = 1.0f;
    } else {
        o0 = __fdiv_rn(bgc[0], 255.0f);
        o1 = __fdiv_rn(bgc[1], 255.0f);
        o2 = __fdiv_rn(bgc[2], 255.0f);
        oa = 0.0f;
    }
    out[3*p+0] = o0;
    out[3*p+1] = o1;
    out[3*p+2] = o2;
    out[(size_t)P*3 + p] = oa;
}

// ---------------------------------------------------------------------------
extern "C" void kernel_launch(void* const* d_in, const int* in_sizes, int n_in,
                              void* d_out, int out_size, void* d_ws, size_t ws_size,
                              hipStream_t stream)
{
    const float* verts = (const float*)d_in[0];
    const float* Km    = (const float*)d_in[1];
    const float* Rm    = (const float*)d_in[2];
    const float* tv    = (const float*)d_in[3];
    const float* bgc   = (const float*)d_in[4];
    const float* tex   = (const float*)d_in[5];
    const int*   faces = (const int*)d_in[6];
    int nF = in_sizes[6] / 3;
    int P = out_size / 4;                 // rgb(3P) + alpha(P)
    int W = (int)(sqrt((double)P) + 0.5);
    int H = W;
    int tilesX = (W + 7) / 8, tilesY = (H + 7) / 8;
    int nTiles = tilesX * tilesY;
    int segw = (nF + NSEG - 1) / NSEG;

    char* ws = (char*)d_ws;
    size_t o = 0;
    auto al = [](size_t x) { return (x + 255) & ~(size_t)255; };
    float4* rec  = (float4*)(ws + o); o = al(o + (size_t)nF * 48);
    float4* box  = (float4*)(ws + o); o = al(o + (size_t)nF * 16);
    float4* rec2 = (float4*)(ws + o); o = al(o + (size_t)nF * 48);
    uint2*  cullrec = (uint2*)(ws + o); o = al(o + (size_t)nF * 8);
    unsigned long long* zwin = (unsigned long long*)(ws + o);
    o = al(o + (size_t)P * 8);
    unsigned* hist = (unsigned*)(ws + o);          // hist[NBIN] + cur[NBIN]
    unsigned* cur  = hist + NBIN;
    o = al(o + (size_t)NBIN * 8);
    unsigned* offb = (unsigned*)(ws + o);
    o = al(o + (size_t)(NBIN + 1) * 4);
    unsigned* segminz = (unsigned*)(ws + o);
    o = al(o + (size_t)NSEG * 4);
    (void)ws_size; (void)n_in;           // ~2.3 MB total scratch

    hipMemsetAsync(hist, 0, (size_t)NBIN * 8, stream);
    k_prep<<<dim3((nF + 63) / 64), dim3(64), 0, stream>>>(
        verts, Km, Rm, tv, faces, rec, box, zwin, segminz, hist, nF, P);
    k_scan<<<dim3(1), dim3(NBIN), 0, stream>>>(hist, offb);
    k_scatter<<<dim3((nF + 63) / 64), dim3(64), 0, stream>>>(
        rec, box, offb, cur, rec2, cullrec, segminz, nF, tilesX, tilesY, segw);
    dim3 g((nTiles + 3) / 4, NSEG, 1);
    k_raster<<<g, dim3(256), 0, stream>>>(
        rec2, cullrec, segminz, zwin, nF, W, H, tilesX, nTiles);
    k_shade<<<dim3((P + 127) / 128), dim3(128), 0, stream>>>(
        rec, zwin, tex, bgc, (float*)d_out, W, H);
}